// Round 2
// baseline (646.446 us; speedup 1.0000x reference)
//
#include <hip/hip_runtime.h>
#include <hip/hip_bf16.h>

// Problem constants (fixed by the reference)
#define NTOT 100000
#define DIM  512
#define CB   4096
#define SSUP 50000
#define NQ   (NTOT - SSUP)

// 256x256-tile GEMM geometry (8-phase schedule)
#define MT2   196             // ceil(50000/256); rows 50000..50175 are query rows, results discarded
#define MPAD2 (MT2 * 256)     // 50176
#define NT2   16              // 4096/256

typedef __bf16 bf16x8 __attribute__((ext_vector_type(8)));
typedef __bf16 bf16x4 __attribute__((ext_vector_type(4)));
typedef float  f32x4  __attribute__((ext_vector_type(4)));

// ---------------- ws layout, fast path (bytes) ----------------
// cbb  : CB*DIM*2          = 4,194,304   @ 0
// Xb   : MPAD2*DIM*2       = 51,380,224  @ 4,194,304
// pv   : MPAD2*16*4        = 3,211,264   @ 55,574,528
// pi   : MPAD2*16*4        = 3,211,264   @ 58,785,792
// protoSum: 2048                         @ 61,997,056
// pcSum : 2048                           @ 61,999,104
// hist  : 16384                          @ 62,001,152
// top_idx: 200,000                       @ 62,017,536
#define OFF_CBBF   0
#define OFF_XB     4194304
#define OFF_PV     55574528
#define OFF_PI     58785792
#define OFF_PSUM   61997056
#define OFF_PCSUM  61999104
#define OFF_HIST   62001152
#define OFF_TIDX   62017536
#define WS_NEED    (62017536 + 200000)
#define ZERO_BYTES (2048 + 2048 + 16384)

// ---------------- ws layout, fallback (round-1) ----------------
#define F_OFF_PSUM   4194304
#define F_OFF_PCSUM  4196352
#define F_OFF_HIST   4198400
#define F_OFF_TIDX   4214784

// ---------------- async global->LDS helper ----------------
__device__ __forceinline__ void load_lds16(const void* g, void* l) {
    __builtin_amdgcn_global_load_lds(
        (const __attribute__((address_space(1))) void*)g,
        (__attribute__((address_space(3))) void*)l, 16, 0, 0);
}

// raw barrier (no implicit vmcnt(0) drain, unlike __syncthreads)
#define BARRIER() __builtin_amdgcn_s_barrier()
#define LGKM0()   do { asm volatile("s_waitcnt lgkmcnt(0)" ::: "memory"); \
                       __builtin_amdgcn_sched_barrier(0); } while (0)
#define VMC(N)    asm volatile("s_waitcnt vmcnt(" #N ")" ::: "memory")

// ---------------- fp32 -> bf16 convert (codebook) ----------------
__global__ void k_convert(const float* __restrict__ src, __bf16* __restrict__ dst) {
    int i = (blockIdx.x * 256 + threadIdx.x) * 4;
    float4 v = *(const float4*)(src + i);
    bf16x4 o;
    o[0] = (__bf16)v.x; o[1] = (__bf16)v.y; o[2] = (__bf16)v.z; o[3] = (__bf16)v.w;
    *(bf16x4*)(dst + i) = o;
}

// ---------------- fused X convert + support column-sum ----------------
// 98 blocks x 256 thr; block covers 512 rows. Thread owns 8 fixed cols,
// 4 row-subgroups per pass. Rows >= SSUP are converted but excluded from sum.
__global__ __launch_bounds__(256)
void k_conv_psum(const float* __restrict__ X, __bf16* __restrict__ Xb,
                 float* __restrict__ protoSum)
{
    __shared__ float red[4][512];
    const int tid  = threadIdx.x;
    const int c8   = (tid & 63) * 8;
    const int rsub = tid >> 6;
    const size_t rbase = (size_t)blockIdx.x * 512 + rsub;

    float acc[8];
    #pragma unroll
    for (int j = 0; j < 8; ++j) acc[j] = 0.f;

    for (int r = 0; r < 512; r += 4) {
        const size_t row = rbase + r;
        const float* p = X + row * DIM + c8;
        float4 v0 = *(const float4*)p;
        float4 v1 = *(const float4*)(p + 4);
        bf16x8 o;
        o[0] = (__bf16)v0.x; o[1] = (__bf16)v0.y; o[2] = (__bf16)v0.z; o[3] = (__bf16)v0.w;
        o[4] = (__bf16)v1.x; o[5] = (__bf16)v1.y; o[6] = (__bf16)v1.z; o[7] = (__bf16)v1.w;
        *(bf16x8*)(Xb + row * DIM + c8) = o;
        if (row < SSUP) {
            acc[0] += v0.x; acc[1] += v0.y; acc[2] += v0.z; acc[3] += v0.w;
            acc[4] += v1.x; acc[5] += v1.y; acc[6] += v1.z; acc[7] += v1.w;
        }
    }
    #pragma unroll
    for (int j = 0; j < 8; ++j) red[rsub][c8 + j] = acc[j];
    __syncthreads();
    if (rsub == 0) {
        #pragma unroll
        for (int j = 0; j < 8; ++j)
            atomicAdd(&protoSum[c8 + j],
                      red[0][c8 + j] + red[1][c8 + j] + red[2][c8 + j] + red[3][c8 + j]);
    }
}

// ---------------- 256^2 8-phase GEMM + fused per-tile argmax ----------------
// BM=BN=256, BK=64, 512 thr = 8 waves (2M x 4N). Per-wave output 128x64.
// LDS 128 KiB: buf0 A @0, buf0 B @32768, buf1 A @65536, buf1 B @98304
// (operand = 256 rows x 128 B; half h = rows h*128.., linear row*128 within).
// T2 swizzle: 16B chunk index c -> c ^ (row&7), applied on BOTH the
// pre-swizzled global source of global_load_lds (linear LDS dest) and the
// ds_read offset (XOR is self-inverse).

__device__ __forceinline__ void stage_half(const __bf16* __restrict__ g, size_t grow0,
                                           int k0, char* ldsop, int half, int tid)
{
    char* dst = ldsop + half * 16384;
    #pragma unroll
    for (int i = 0; i < 2; ++i) {
        const int ck  = i * 512 + tid;   // 0..1023, 16 B each; wave-linear dest
        const int row = ck >> 3;         // 0..127 within half
        const int sc  = (ck & 7) ^ (row & 7);
        load_lds16(g + (grow0 + (size_t)row) * DIM + k0 + sc * 8, dst + ck * 16);
    }
}

template<int BUFOFF, int MH>
__device__ __forceinline__ void ds_load_A(const char* aptr, int off0, int off1,
                                          bf16x8 (&a)[4][2])
{
    #pragma unroll
    for (int t = 0; t < 4; ++t) {
        const char* p = aptr + BUFOFF + MH * 8192 + t * 2048;
        a[t][0] = *(const bf16x8*)(p + off0);
        a[t][1] = *(const bf16x8*)(p + off1);
    }
}

template<int BUFOFF, int NH>
__device__ __forceinline__ void ds_load_B(const char* bptr, int off0, int off1,
                                          bf16x8 (&b)[2][2])
{
    #pragma unroll
    for (int n = 0; n < 2; ++n) {
        const char* p = bptr + BUFOFF + NH * 4096 + n * 2048;
        b[n][0] = *(const bf16x8*)(p + off0);
        b[n][1] = *(const bf16x8*)(p + off1);
    }
}

template<int MH, int NH>
__device__ __forceinline__ void mfma_quad(const bf16x8 (&a)[4][2], const bf16x8 (&b)[2][2],
                                          f32x4 (&acc)[8][4])
{
    __builtin_amdgcn_s_setprio(1);
    #pragma unroll
    for (int t = 0; t < 4; ++t)
        #pragma unroll
        for (int n = 0; n < 2; ++n)
            #pragma unroll
            for (int ks = 0; ks < 2; ++ks)
                acc[MH * 4 + t][NH * 2 + n] = __builtin_amdgcn_mfma_f32_16x16x32_bf16(
                    a[t][ks], b[n][ks], acc[MH * 4 + t][NH * 2 + n], 0, 0, 0);
    __builtin_amdgcn_s_setprio(0);
    __builtin_amdgcn_sched_barrier(0);
}

__global__ __launch_bounds__(512, 2)
void k_gemm256(const __bf16* __restrict__ Xb, const __bf16* __restrict__ cbb,
               float* __restrict__ pv, int* __restrict__ pi)
{
    __shared__ __align__(16) char lds[131072];

    const int tid  = threadIdx.x;
    const int lane = tid & 63;
    const int wid  = tid >> 6;
    const int wm   = wid >> 2;            // 0..1
    const int wn   = wid & 3;             // 0..3
    const int l15  = lane & 15;
    const int q    = lane >> 4;
    const int nt   = blockIdx.x;          // 0..15
    const int mt   = blockIdx.y;          // 0..195
    const size_t r0  = (size_t)mt * 256;
    const size_t c0g = (size_t)nt * 256;

    // swizzled ds_read byte offsets (chunk = ks*4+q, row&7 == l15&7)
    const int off0 = l15 * 128 + ((q)     ^ (l15 & 7)) * 16;   // ks=0
    const int off1 = l15 * 128 + ((4 + q) ^ (l15 & 7)) * 16;   // ks=1
    const char* aptr = lds + wm * 16384;   // + wm*128 rows
    const char* bptr = lds + wn * 8192;    // + wn*64 rows

    f32x4 acc[8][4];
    #pragma unroll
    for (int i = 0; i < 8; ++i)
        #pragma unroll
        for (int j = 0; j < 4; ++j)
            acc[i][j] = (f32x4){0.f, 0.f, 0.f, 0.f};

    bf16x8 a[4][2], b0[2][2], b1[2][2];

    // ---- prologue: tile0 full (buf0) + tile1 B-halves (buf1). 12 loads, keep 4 in flight.
    stage_half(Xb,  r0,        0,  lds + 0,     0, tid);
    stage_half(Xb,  r0 + 128,  0,  lds + 0,     1, tid);
    stage_half(cbb, c0g,       0,  lds + 32768, 0, tid);
    stage_half(cbb, c0g + 128, 0,  lds + 32768, 1, tid);
    stage_half(cbb, c0g,       64, lds + 98304, 0, tid);
    stage_half(cbb, c0g + 128, 64, lds + 98304, 1, tid);
    VMC(4);
    BARRIER();

    // ---- main loop: iteration processes tiles u=2it (buf0, ph1-4), u+1 (buf1, ph5-8).
    // Stage ledger (race-free: stage of region issued >= 1 barrier-pair after its
    // last ds_read; buffer-switch reads gated by vmcnt(4)+barrier at ph4/ph8):
    //  ph1: A.lo(u+1)->buf1  ph2: A.hi(u+1)->buf1  ph3: B.lo(u+2)->buf0
    //  ph4: B.hi(u+2)->buf0 +vmcnt(4)              ph5: A.lo(u+2)->buf0
    //  ph6: A.hi(u+2)->buf0  ph7: B.lo(u+3)->buf1  ph8: B.hi(u+3)->buf1 +vmcnt(4)
    #pragma unroll 1
    for (int it = 0; it < 3; ++it) {
        const int kA1 = (2 * it + 1) * 64;
        const int k2  = (2 * it + 2) * 64;
        const int kB3 = (2 * it + 3) * 64;
        // ph1: buf0 quad(0,0)
        ds_load_A<0, 0>(aptr, off0, off1, a);
        ds_load_B<32768, 0>(bptr, off0, off1, b0);
        stage_half(Xb, r0, kA1, lds + 65536, 0, tid);
        BARRIER(); LGKM0();
        mfma_quad<0, 0>(a, b0, acc);
        BARRIER();
        // ph2: buf0 quad(0,1)
        ds_load_B<32768, 1>(bptr, off0, off1, b1);
        stage_half(Xb, r0 + 128, kA1, lds + 65536, 1, tid);
        BARRIER(); LGKM0();
        mfma_quad<0, 1>(a, b1, acc);
        BARRIER();
        // ph3: buf0 quad(1,1)
        ds_load_A<0, 1>(aptr, off0, off1, a);
        stage_half(cbb, c0g, k2, lds + 32768, 0, tid);
        BARRIER(); LGKM0();
        mfma_quad<1, 1>(a, b1, acc);
        BARRIER();
        // ph4: buf0 quad(1,0); tile u+1 guaranteed landed after vmcnt(4)+barrier
        stage_half(cbb, c0g + 128, k2, lds + 32768, 1, tid);
        VMC(4);
        BARRIER();
        mfma_quad<1, 0>(a, b0, acc);
        BARRIER();
        // ph5: buf1 quad(0,0)
        ds_load_A<65536, 0>(aptr, off0, off1, a);
        ds_load_B<98304, 0>(bptr, off0, off1, b0);
        stage_half(Xb, r0, k2, lds + 0, 0, tid);
        BARRIER(); LGKM0();
        mfma_quad<0, 0>(a, b0, acc);
        BARRIER();
        // ph6: buf1 quad(0,1)
        ds_load_B<98304, 1>(bptr, off0, off1, b1);
        stage_half(Xb, r0 + 128, k2, lds + 0, 1, tid);
        BARRIER(); LGKM0();
        mfma_quad<0, 1>(a, b1, acc);
        BARRIER();
        // ph7: buf1 quad(1,1)
        ds_load_A<65536, 1>(aptr, off0, off1, a);
        stage_half(cbb, c0g, kB3, lds + 98304, 0, tid);
        BARRIER(); LGKM0();
        mfma_quad<1, 1>(a, b1, acc);
        BARRIER();
        // ph8: buf1 quad(1,0); tile u+2 guaranteed landed
        stage_half(cbb, c0g + 128, kB3, lds + 98304, 1, tid);
        VMC(4);
        BARRIER();
        mfma_quad<1, 0>(a, b0, acc);
        BARRIER();
    }

    // ---- epilogue: tiles 6 (buf0) and 7 (buf1); drain to vmcnt(0) once.
    {
        const int k7 = 7 * 64;
        ds_load_A<0, 0>(aptr, off0, off1, a);
        ds_load_B<32768, 0>(bptr, off0, off1, b0);
        stage_half(Xb, r0, k7, lds + 65536, 0, tid);
        BARRIER(); LGKM0();
        mfma_quad<0, 0>(a, b0, acc);
        BARRIER();

        ds_load_B<32768, 1>(bptr, off0, off1, b1);
        stage_half(Xb, r0 + 128, k7, lds + 65536, 1, tid);
        BARRIER(); LGKM0();
        mfma_quad<0, 1>(a, b1, acc);
        BARRIER();

        ds_load_A<0, 1>(aptr, off0, off1, a);
        BARRIER(); LGKM0();
        mfma_quad<1, 1>(a, b1, acc);
        BARRIER();

        VMC(0);
        BARRIER();
        mfma_quad<1, 0>(a, b0, acc);
        BARRIER();

        ds_load_A<65536, 0>(aptr, off0, off1, a);
        ds_load_B<98304, 0>(bptr, off0, off1, b0);
        BARRIER(); LGKM0();
        mfma_quad<0, 0>(a, b0, acc);
        BARRIER();

        ds_load_B<98304, 1>(bptr, off0, off1, b1);
        BARRIER(); LGKM0();
        mfma_quad<0, 1>(a, b1, acc);
        BARRIER();

        ds_load_A<65536, 1>(aptr, off0, off1, a);
        BARRIER(); LGKM0();
        mfma_quad<1, 1>(a, b1, acc);
        BARRIER();

        mfma_quad<1, 0>(a, b0, acc);
    }

    // ---- fused argmax over the block's 256 cols.
    // C/D: col = c0 + wn*64 + fn*16 + l15 ; row = r0 + wm*128 + fm*16 + q*4 + reg
    // LDS reuse (buf0-A rows 0..63; last ds_read of that region completed >=5 barriers ago,
    // and all VMEM landed at the epilogue vmcnt(0)).
    float* sv = (float*)lds;               // [256][4]
    int*   si = (int*)(lds + 4096);        // [256][4]
    #pragma unroll
    for (int fm = 0; fm < 8; ++fm) {
        #pragma unroll
        for (int reg = 0; reg < 4; ++reg) {
            float v = -3.0e38f; int idx = 0;
            #pragma unroll
            for (int fn = 0; fn < 4; ++fn) {
                float x = acc[fm][fn][reg];
                int   c = (int)c0g + wn * 64 + fn * 16 + l15;
                if (x > v) { v = x; idx = c; }
            }
            #pragma unroll
            for (int off = 1; off < 16; off <<= 1) {
                float ov = __shfl_xor(v, off, 64);
                int   oi = __shfl_xor(idx, off, 64);
                if (ov > v) { v = ov; idx = oi; }
            }
            if (l15 == 0) {
                int rl = wm * 128 + fm * 16 + q * 4 + reg;
                sv[rl * 4 + wn] = v;
                si[rl * 4 + wn] = idx;
            }
        }
    }
    __syncthreads();
    if (tid < 256) {
        float v = sv[tid * 4]; int idx = si[tid * 4];
        #pragma unroll
        for (int j = 1; j < 4; ++j) {
            float x = sv[tid * 4 + j];
            if (x > v) { v = x; idx = si[tid * 4 + j]; }
        }
        size_t r = r0 + tid;
        pv[r * 16 + nt] = v;
        pi[r * 16 + nt] = idx;
    }
}

// ---------------- phase-2: reduce 16 tile-partials per row ----------------
__global__ void k_argmax_reduce16(const float* __restrict__ pv, const int* __restrict__ pi,
                                  int* __restrict__ top_idx) {
    int r = blockIdx.x * 256 + threadIdx.x;
    if (r >= SSUP) return;
    float v = -3.0e38f; int idx = 0;
    #pragma unroll
    for (int j = 0; j < 16; ++j) {
        float x = pv[(size_t)r * 16 + j];
        if (x > v) { v = x; idx = pi[(size_t)r * 16 + j]; }
    }
    top_idx[r] = idx;
}

// ---------------- column sums of support (fallback path) ----------------
__global__ void k_proto_sum(const float* __restrict__ X, float* __restrict__ protoSum) {
    const int d = threadIdx.x;              // 512 threads
    const int r0 = blockIdx.x * 500;        // 100 blocks x 500 rows
    float acc = 0.f;
    for (int r = r0; r < r0 + 500; ++r)
        acc += X[(size_t)r * DIM + d];
    atomicAdd(&protoSum[d], acc);
}

// ---------------- fallback GEMM (round-1, known-correct) ----------------
__global__ __launch_bounds__(256, 2)
void k_gemm_argmax(const float* __restrict__ X, const __bf16* __restrict__ cbb,
                   int* __restrict__ top_idx)
{
    __shared__ float redv[64][2];
    __shared__ int   redi[64][2];

    const int tid  = threadIdx.x;
    const int wave = tid >> 6;
    const int lane = tid & 63;
    const int wm   = wave >> 1;
    const int wn   = wave & 1;
    const int l15  = lane & 15;
    const int q    = lane >> 4;
    const int r0   = blockIdx.x * 64;

    bf16x8 aflat[2][16];
    #pragma unroll
    for (int tm = 0; tm < 2; ++tm) {
        const int r = r0 + wm * 32 + tm * 16 + l15;
        const bool valid = (r < SSUP);
        const float* xr = X + (size_t)r * DIM + q * 8;
        #pragma unroll
        for (int kt = 0; kt < 16; ++kt) {
            float4 v0, v1;
            if (valid) {
                v0 = *(const float4*)(xr + kt * 32);
                v1 = *(const float4*)(xr + kt * 32 + 4);
            } else {
                v0 = make_float4(0.f, 0.f, 0.f, 0.f);
                v1 = v0;
            }
            bf16x8 f;
            f[0] = (__bf16)v0.x; f[1] = (__bf16)v0.y; f[2] = (__bf16)v0.z; f[3] = (__bf16)v0.w;
            f[4] = (__bf16)v1.x; f[5] = (__bf16)v1.y; f[6] = (__bf16)v1.z; f[7] = (__bf16)v1.w;
            aflat[tm][kt] = f;
        }
    }

    float mx[8];
    int   mi[8];
    #pragma unroll
    for (int i = 0; i < 8; ++i) { mx[i] = -3.0e38f; mi[i] = 0; }
    const f32x4 zero4 = {0.f, 0.f, 0.f, 0.f};

    for (int ct = 0; ct < 32; ++ct) {
        const int c0 = ct * 128 + wn * 64;
        const __bf16* bptr[4];
        #pragma unroll
        for (int tn = 0; tn < 4; ++tn)
            bptr[tn] = cbb + (size_t)(c0 + tn * 16 + l15) * DIM + q * 8;

        f32x4 acc[2][4];
        #pragma unroll
        for (int i = 0; i < 2; ++i)
            #pragma unroll
            for (int j = 0; j < 4; ++j)
                acc[i][j] = zero4;

        #pragma unroll
        for (int kt = 0; kt < 16; ++kt) {
            bf16x8 b[4];
            #pragma unroll
            for (int tn = 0; tn < 4; ++tn)
                b[tn] = *(const bf16x8*)(bptr[tn] + kt * 32);
            #pragma unroll
            for (int tm = 0; tm < 2; ++tm)
                #pragma unroll
                for (int tn = 0; tn < 4; ++tn)
                    acc[tm][tn] = __builtin_amdgcn_mfma_f32_16x16x32_bf16(
                        aflat[tm][kt], b[tn], acc[tm][tn], 0, 0, 0);
        }
        #pragma unroll
        for (int tm = 0; tm < 2; ++tm)
            #pragma unroll
            for (int tn = 0; tn < 4; ++tn)
                #pragma unroll
                for (int reg = 0; reg < 4; ++reg) {
                    float v = acc[tm][tn][reg];
                    int slot = tm * 4 + reg;
                    int col  = c0 + tn * 16 + l15;
                    if (v > mx[slot]) { mx[slot] = v; mi[slot] = col; }
                }
    }

    #pragma unroll
    for (int slot = 0; slot < 8; ++slot) {
        float v  = mx[slot];
        int  idx = mi[slot];
        #pragma unroll
        for (int off = 1; off < 16; off <<= 1) {
            float ov = __shfl_xor(v, off, 64);
            int   oi = __shfl_xor(idx, off, 64);
            if (ov > v) { v = ov; idx = oi; }
        }
        if (l15 == 0) {
            int rowl = wm * 32 + (slot >> 2) * 16 + q * 4 + (slot & 3);
            redv[rowl][wn] = v;
            redi[rowl][wn] = idx;
        }
    }
    __syncthreads();
    if (tid < 64) {
        int r = r0 + tid;
        if (r < SSUP) {
            float v0 = redv[tid][0], v1 = redv[tid][1];
            top_idx[r] = (v1 > v0) ? redi[tid][1] : redi[tid][0];
        }
    }
}

// ---------------- histogram of top_idx ----------------
__global__ void k_hist(const int* __restrict__ top_idx, int* __restrict__ hist) {
    __shared__ int lh[CB];
    for (int i = threadIdx.x; i < CB; i += blockDim.x) lh[i] = 0;
    __syncthreads();
    for (int i = blockIdx.x * blockDim.x + threadIdx.x; i < SSUP; i += gridDim.x * blockDim.x)
        atomicAdd(&lh[top_idx[i]], 1);
    __syncthreads();
    for (int i = threadIdx.x; i < CB; i += blockDim.x) {
        int v = lh[i];
        if (v) atomicAdd(&hist[i], v);
    }
}

// ---------------- weighted codebook sum (proto_code * S) ----------------
__global__ void k_proto_code(const float* __restrict__ cb, const int* __restrict__ hist,
                             float* __restrict__ pcSum) {
    const int d  = threadIdx.x;          // 512 threads
    const int c0 = blockIdx.x * 64;
    float acc = 0.f;
    for (int c = c0; c < c0 + 64; ++c) {
        float w = (float)hist[c];
        if (w != 0.f) acc += w * cb[(size_t)c * DIM + d];
    }
    atomicAdd(&pcSum[d], acc);
}

// ---------------- query scores ----------------
__global__ void k_query(const float* __restrict__ X, const float* __restrict__ protoSum,
                        const float* __restrict__ pcSum, float* __restrict__ out) {
    const int lane   = threadIdx.x & 63;
    const int waveId = (blockIdx.x * blockDim.x + threadIdx.x) >> 6;
    const int nwaves = (gridDim.x * blockDim.x) >> 6;
    const float invS = 1.0f / (float)SSUP;

    for (int r = waveId; r < NQ; r += nwaves) {
        const float* xr = X + (size_t)(SSUP + r) * DIM;
        float s1 = 0.f, s2 = 0.f;
        #pragma unroll
        for (int i = 0; i < 2; ++i) {
            int dd = lane * 4 + i * 256;
            float4 xq = *(const float4*)(xr + dd);
            float4 p  = *(const float4*)(protoSum + dd);
            float4 pc = *(const float4*)(pcSum + dd);
            float d0, d1, d2, d3;
            d0 = xq.x - p.x * invS; d1 = xq.y - p.y * invS;
            d2 = xq.z - p.z * invS; d3 = xq.w - p.w * invS;
            s1 += d0 * d0 + d1 * d1 + d2 * d2 + d3 * d3;
            d0 = xq.x - pc.x * invS; d1 = xq.y - pc.y * invS;
            d2 = xq.z - pc.z * invS; d3 = xq.w - pc.w * invS;
            s2 += d0 * d0 + d1 * d1 + d2 * d2 + d3 * d3;
        }
        #pragma unroll
        for (int off = 32; off > 0; off >>= 1) {
            s1 += __shfl_xor(s1, off, 64);
            s2 += __shfl_xor(s2, off, 64);
        }
        if (lane == 0)
            out[r] = 0.5f * (sqrtf(s1) + sqrtf(s2));
    }
}

extern "C" void kernel_launch(void* const* d_in, const int* in_sizes, int n_in,
                              void* d_out, int out_size, void* d_ws, size_t ws_size,
                              hipStream_t stream) {
    const float* X  = (const float*)d_in[0];
    const float* cb = (const float*)d_in[1];
    float* out = (float*)d_out;
    char* ws = (char*)d_ws;

    __bf16* cbb = (__bf16*)(ws + OFF_CBBF);

    if (ws_size >= (size_t)WS_NEED) {
        // ---- fast path: 256^2 8-phase tiled GEMM
        __bf16* Xb       = (__bf16*)(ws + OFF_XB);
        float*  pv       = (float*)(ws + OFF_PV);
        int*    pi       = (int*)(ws + OFF_PI);
        float*  protoSum = (float*)(ws + OFF_PSUM);
        float*  pcSum    = (float*)(ws + OFF_PCSUM);
        int*    hist     = (int*)(ws + OFF_HIST);
        int*    top_idx  = (int*)(ws + OFF_TIDX);

        hipMemsetAsync(ws + OFF_PSUM, 0, ZERO_BYTES, stream);

        k_convert<<<(CB * DIM) / 1024, 256, 0, stream>>>(cb, cbb);
        k_conv_psum<<<MPAD2 / 512, 256, 0, stream>>>(X, Xb, protoSum);

        dim3 grid(NT2, MT2);
        k_gemm256<<<grid, 512, 0, stream>>>(Xb, cbb, pv, pi);

        k_argmax_reduce16<<<(SSUP + 255) / 256, 256, 0, stream>>>(pv, pi, top_idx);
        k_hist<<<64, 256, 0, stream>>>(top_idx, hist);
        k_proto_code<<<CB / 64, 512, 0, stream>>>(cb, hist, pcSum);
        k_query<<<1024, 256, 0, stream>>>(X, protoSum, pcSum, out);
    } else {
        // ---- fallback: round-1 path (needs only ~4.4 MB)
        float*  protoSum = (float*)(ws + F_OFF_PSUM);
        float*  pcSum    = (float*)(ws + F_OFF_PCSUM);
        int*    hist     = (int*)(ws + F_OFF_HIST);
        int*    top_idx  = (int*)(ws + F_OFF_TIDX);

        hipMemsetAsync(ws + F_OFF_PSUM, 0, ZERO_BYTES, stream);

        k_convert<<<(CB * DIM) / 1024, 256, 0, stream>>>(cb, cbb);
        k_proto_sum<<<100, 512, 0, stream>>>(X, protoSum);
        k_gemm_argmax<<<(SSUP + 63) / 64, 256, 0, stream>>>(X, cbb, top_idx);
        k_hist<<<64, 256, 0, stream>>>(top_idx, hist);
        k_proto_code<<<CB / 64, 512, 0, stream>>>(cb, hist, pcSum);
        k_query<<<1024, 256, 0, stream>>>(X, protoSum, pcSum, out);
    }
}